// Round 1
// baseline (260.093 us; speedup 1.0000x reference)
//
#include <hip/hip_runtime.h>
#include <stdint.h>

// Problem constants
#define BATCH 512
#define HWIMG 78400      // 280*280
#define WROW  280
#define PNUM  100        // 10x10 patches
#define FNUM  16
#define ONUM  10

__global__ __launch_bounds__(256) void init_out(const float* __restrict__ dec_b,
                                                float* __restrict__ out) {
    int i = blockIdx.x * 256 + threadIdx.x;
    if (i < BATCH * ONUM) out[i] = dec_b[i % ONUM];
}

// One wave (64 threads) per block. Wave owns (patch p, 16 batches), all 16 filters.
// No LDS, no barriers: x is streamed straight into registers (per-lane float4 loads;
// the 28 lanes of a kg-cluster + fg same-address merging cover 112-B contiguous row
// segments, so coalescing is fine without LDS re-staging). w comes from L2 (50 KB per
// patch, shared by the 32 waves that handle the same p). All reductions are intra-wave.
//   Lane map: kg = t&7 (7 float4 k-columns + 1 duplicate, masked), fg = (t>>3)&3
//   (filter quad), bg = t>>5 (which 8 of the wave's 16 batches).
// Occupancy: zero LDS, VGPR capped at 128 -> 16 waves/CU, all free-running.
__global__ __launch_bounds__(64, 4) void lcn_direct(
    const float* __restrict__ x,      // (512,1,280,280)
    const float* __restrict__ weight, // (1600,1,28,28)  index (f*100+p)*784
    const float* __restrict__ bias,   // (1600,1)        index  f*100+p
    const float* __restrict__ dec_w,  // (10,1600)       index  o*1600+f*100+p
    float* __restrict__ out)          // (512,10) pre-initialized with dec_b
{
    const int t  = threadIdx.x;       // 0..63
    const int kg = t & 7;             // k-slice: float4 column within row
    const int fg = (t >> 3) & 3;      // filter group
    const int bg = t >> 5;            // batch oct 0..1
    const int bx = blockIdx.x;        // 0..3199
    const int p    = bx >> 5;         // 0..99  (32 consecutive blocks share p -> warm w)
    const int bgrp = bx & 31;         // 0..31
    const int b0   = bgrp * 16;
    const int pr = p / 10, pc = p % 10;
    const int kge = (kg < 7) ? kg : 0;   // kg==7 duplicates kg==0, masked later

    // Per-lane base pointers. Chunk offsets folded into pointer increments so all
    // per-load offsets are small compile-time immediates.
    const float* xb[8];
#pragma unroll
    for (int i = 0; i < 8; ++i)
        xb[i] = x + (size_t)(b0 + bg * 8 + i) * HWIMG
                  + (size_t)(pr * 28) * WROW + pc * 28 + kge * 4;
    const float* wb[4];
#pragma unroll
    for (int j = 0; j < 4; ++j)
        wb[j] = weight + (size_t)((fg * 4 + j) * PNUM + p) * 784 + kge * 4;

    float acc[8][4];
#pragma unroll
    for (int i = 0; i < 8; ++i)
#pragma unroll
        for (int j = 0; j < 4; ++j) acc[i][j] = 0.f;

    // 7 chunks of 4 rows = 28 rows. c-loop NOT unrolled (keeps code in I-cache);
    // m/i/j fully unrolled for static addressing + ILP.
#pragma unroll 1
    for (int c = 0; c < 7; ++c) {
#pragma unroll
        for (int m = 0; m < 4; ++m) {
            float4 wv[4];
#pragma unroll
            for (int j = 0; j < 4; ++j)
                wv[j] = *reinterpret_cast<const float4*>(wb[j] + m * 28);
#pragma unroll
            for (int i = 0; i < 8; ++i) {
                float4 av = *reinterpret_cast<const float4*>(xb[i] + m * WROW);
#pragma unroll
                for (int j = 0; j < 4; ++j) {
                    acc[i][j] = fmaf(av.x, wv[j].x, acc[i][j]);
                    acc[i][j] = fmaf(av.y, wv[j].y, acc[i][j]);
                    acc[i][j] = fmaf(av.z, wv[j].z, acc[i][j]);
                    acc[i][j] = fmaf(av.w, wv[j].w, acc[i][j]);
                }
            }
        }
#pragma unroll
        for (int i = 0; i < 8; ++i) xb[i] += 4 * WROW;
#pragma unroll
        for (int j = 0; j < 4; ++j) wb[j] += 4 * 28;
    }

    // kg==7 computed duplicated data: zero it.
    const float km = (kg < 7) ? 1.f : 0.f;
#pragma unroll
    for (int i = 0; i < 8; ++i)
#pragma unroll
        for (int j = 0; j < 4; ++j) acc[i][j] *= km;

    // Reduce over kg (lane bits 0..2) — butterfly; all lanes end with the sum.
#pragma unroll
    for (int d = 1; d < 8; d <<= 1)
#pragma unroll
        for (int i = 0; i < 8; ++i)
#pragma unroll
            for (int j = 0; j < 4; ++j)
                acc[i][j] += __shfl_xor(acc[i][j], d, 64);

    // bias + relu
    float y[8][4];
#pragma unroll
    for (int j = 0; j < 4; ++j) {
        const float bs = bias[(fg * 4 + j) * PNUM + p];
#pragma unroll
        for (int i = 0; i < 8; ++i) {
            float v = acc[i][j] + bs;
            y[i][j] = v > 0.f ? v : 0.f;
        }
    }

    // Decoder: split the 10 outputs across kg lanes 0..4 (2 outputs each).
    float po[8][2];
    const int  o0  = kg * 2;
    const bool act = (kg < 5);
    if (act) {
        float dwv[4][2];
#pragma unroll
        for (int j = 0; j < 4; ++j)
#pragma unroll
            for (int oo = 0; oo < 2; ++oo)
                dwv[j][oo] = dec_w[(size_t)(o0 + oo) * (PNUM * FNUM) + (fg * 4 + j) * PNUM + p];
#pragma unroll
        for (int i = 0; i < 8; ++i)
#pragma unroll
            for (int oo = 0; oo < 2; ++oo) {
                float s = 0.f;
#pragma unroll
                for (int j = 0; j < 4; ++j) s = fmaf(y[i][j], dwv[j][oo], s);
                po[i][oo] = s;
            }
    } else {
#pragma unroll
        for (int i = 0; i < 8; ++i) { po[i][0] = 0.f; po[i][1] = 0.f; }
    }

    // Reduce over fg (lane bits 3..4); kg/bg bits preserved so zero lanes stay isolated.
#pragma unroll
    for (int d = 8; d < 32; d <<= 1)
#pragma unroll
        for (int i = 0; i < 8; ++i)
#pragma unroll
            for (int oo = 0; oo < 2; ++oo)
                po[i][oo] += __shfl_xor(po[i][oo], d, 64);

    if (act && fg == 0) {
#pragma unroll
        for (int i = 0; i < 8; ++i)
#pragma unroll
            for (int oo = 0; oo < 2; ++oo)
                atomicAdd(&out[(size_t)(b0 + bg * 8 + i) * ONUM + o0 + oo], po[i][oo]);
    }
}

extern "C" void kernel_launch(void* const* d_in, const int* in_sizes, int n_in,
                              void* d_out, int out_size, void* d_ws, size_t ws_size,
                              hipStream_t stream) {
    const float* x     = (const float*)d_in[0];
    const float* w     = (const float*)d_in[1];
    const float* bias  = (const float*)d_in[2];
    const float* dec_w = (const float*)d_in[3];
    const float* dec_b = (const float*)d_in[4];
    float* out = (float*)d_out;

    init_out<<<(BATCH * ONUM + 255) / 256, 256, 0, stream>>>(dec_b, out);
    lcn_direct<<<(BATCH / 16) * PNUM, 64, 0, stream>>>(x, w, bias, dec_w, out);
}